// Round 12
// baseline (314.339 us; speedup 1.0000x reference)
//
#include <hip/hip_runtime.h>
#include <math.h>

#define BB 8
#define CC 256
#define KK 19
#define HW 16384
#define HW4 4096            // HW / 4 (float4 units)

#define SCH4 64             // float4 per s-chunk = 256 floats
#define NS2 (HW4 / SCH4)    // 64 s-chunks per batch

// ---- K1 history ----
// r1: LDS map broadcast + per-lane feature: 93 us.
// r2/r3: bigger tiles -> 64-VGPR pin -> scratch GBs. Design inside 64 VGPRs.
// r4/r5: map->SGPR asm; per-j lgkmcnt(0) drain = 100 us.
// r6: constant-AS map (compiler s_load) + global_load_lds staging + swizzle:
//     K1 ~75-80 us, total 281. Best.
// r7: DS reads/conflicts halved -> NO change. r8: direct per-lane feature:
//     134 us (64-line gather). r9: hand-asm pipeline: crash. r10: SMEM
//     drains halved -> NO change. r11: LDS halved (occupancy 2x) -> slightly
//     WORSE. Surviving theory: the __syncthreads structure itself — every
//     barrier re-syncs all 4 waves, so stalls are taken in lockstep and
//     nothing covers them.
// r12 (this): delete ALL barriers. Channel-split (wave owns 64 channels,
//     thread = channel) -> staging is wave-private -> per-wave counted
//     s_waitcnt vmcnt(8) pipeline (stage t+1 while computing t; loads stay
//     in flight across phases, never a block-wide drain). Map: 19 SGPR rows
//     per j (r8 structure; r8's failure attributed to the feature gather,
//     now staged+coalesced). 64 KB LDS/block, grid 512, K1b/K2 frozen.

typedef float f32x4 __attribute__((ext_vector_type(4)));

#define AS1C(p) ((const __attribute__((address_space(1))) void*)(p))
#define AS3(p)  ((__attribute__((address_space(3))) void*)(p))

// Constant-AS vector pointer: uniform address + read-only memory -> s_load.
typedef const __attribute__((address_space(4))) f32x4* cvec4p;
#define CVEC4(p) ((cvec4p)(unsigned long long)(p))

// Macro-unrolled k loops: literal indices -> SROA -> registers.
#define FOR_K(OP) OP(0) OP(1) OP(2) OP(3) OP(4) OP(5) OP(6) OP(7) OP(8) OP(9) \
                  OP(10) OP(11) OP(12) OP(13) OP(14) OP(15) OP(16) OP(17) OP(18)

// Per-wave counted wait: allows N loads to stay outstanding. sched_barrier
// keeps the following ds_reads from hoisting above the wait (rule-18 analog).
#define WVM(N) do {                                                      \
    asm volatile("s_waitcnt vmcnt(" #N ")" ::: "memory");                \
    __builtin_amdgcn_sched_barrier(0);                                   \
} while (0)

__global__ __launch_bounds__(256) void CGM_k1_contract(
    const float* __restrict__ feature,
    const float* __restrict__ map_,
    float* __restrict__ att,        // fallback target (pre-zeroed)
    float* __restrict__ part)       // [KK][BB][NS2][CC] partials, or nullptr
{
    const int bI = blockIdx.x;      // b*NS2 + s
    const int s  = bI & (NS2 - 1);
    const int b  = bI >> 6;         // NS2 == 64
    const int t  = threadIdx.x;
    const int l  = t & 63;
    const int w  = t >> 6;          // wave id 0..3 -> channels w*64 + l

    // 64 KB: per-wave double-buffered tile [64 rows][8 float4].
    __shared__ float4 buf[4][2][512];

    // Map row pointers: blockIdx-derived only -> uniform -> s_load_dwordx4,
    // compiler-scheduled (batched per j, counted lgkm waits).
    const float* mw = map_ + (size_t)b * KK * HW + (size_t)s * (SCH4 * 4);
#define DECLM(K) cvec4p cm##K = CVEC4(mw + (size_t)(K) * HW);
    FOR_K(DECLM)
#undef DECLM

    const float4* fbase = (const float4*)feature
                        + ((size_t)b * CC + w * 64) * HW4 + s * SCH4;

    float acc[KK];
#define ZERO(K) acc[K] = 0.f;
    FOR_K(ZERO)
#undef ZERO

    // Stage tile JT into this wave's buffer PP: 8 issues x 64 lanes x 16 B.
    // Linear LDS dest (uniform base + lane*16) + inverse-swizzled global
    // source (involution js^(row&7), r6-validated).
#define STAGE(PP, JT) do {                                               \
    __builtin_amdgcn_sched_barrier(0);                                   \
    _Pragma("unroll")                                                    \
    for (int q = 0; q < 8; ++q) {                                        \
        const int slot = q * 64 + l;                                     \
        const int row  = slot >> 3;                                      \
        const int js   = slot & 7;                                       \
        const float4* g = fbase + (size_t)row * HW4                      \
                        + (JT) * 8 + (js ^ (row & 7));                   \
        __builtin_amdgcn_global_load_lds(AS1C(g),                        \
            AS3(&buf[w][PP][slot]), 16, 0, 0);                           \
    }                                                                    \
} while (0)

    // Compute tile JT from wave buffer PP: per j, 19 SGPR map quads feed
    // one swizzled ds_read_b128 (row l) and 76 FMAs.
    // Swizzle: LDS[row][js] = G[row][js^(row&7)]; read LDS[l][j^(l&7)] = G[l][j].
#define STEP(K) { const f32x4 m = cm##K[jj];                             \
                  acc[K] += fv.x * m.x + fv.y * m.y + fv.z * m.z + fv.w * m.w; }
#define COMPUTE(PP, JT) do {                                             \
    _Pragma("unroll")                                                    \
    for (int j = 0; j < 8; ++j) {                                        \
        const int jj = (JT) * 8 + j;                                     \
        const float4 fv = buf[w][PP][l * 8 + (j ^ (l & 7))];             \
        FOR_K(STEP)                                                      \
    }                                                                    \
} while (0)

    // Per-wave software pipeline over the 8 j-tiles, depth 2, NO barriers.
    // Each WVM(8) leaves the newest 8 staging loads in flight.
    STAGE(0, 0); STAGE(1, 1);
    WVM(8); COMPUTE(0, 0); STAGE(0, 2);
    WVM(8); COMPUTE(1, 1); STAGE(1, 3);
    WVM(8); COMPUTE(0, 2); STAGE(0, 4);
    WVM(8); COMPUTE(1, 3); STAGE(1, 5);
    WVM(8); COMPUTE(0, 4); STAGE(0, 6);
    WVM(8); COMPUTE(1, 5); STAGE(1, 7);
    WVM(8); COMPUTE(0, 6);
    WVM(0); COMPUTE(1, 7);

#undef STAGE
#undef COMPUTE
#undef STEP

    if (part) {
        // part[k][b][s][c]: per k one coalesced 1 KB block store (c = t).
#define FIN(K) { part[((size_t)((K) * BB + b) * NS2 + s) * CC + t] = acc[K]; }
        FOR_K(FIN)
#undef FIN
    } else {
        // Fallback: fp32 atomics into pre-zeroed att.
#define FIN(K) atomicAdd(&att[(size_t)(b * CC + t) * KK + (K)], acc[K]);
        FOR_K(FIN)
#undef FIN
    }
}

// ---- K1b: fold the NS2=64 s-chunk partials into att (validated r10). ----
__global__ __launch_bounds__(256) void CGM_k1b_reduce(
    const float* __restrict__ part,
    float* __restrict__ att)
{
    const int bk = blockIdx.x;      // b*KK + k
    const int b  = bk / KK;
    const int k  = bk - b * KK;
    const int t  = threadIdx.x;
    const int q  = t & 63;          // float4 column: channels 4q..4q+3
    const int sg = t >> 6;          // s quarter: 16 rows

    const float4* p4 = (const float4*)(part + (size_t)(k * BB + b) * NS2 * CC)
                     + (size_t)(sg * 16) * 64 + q;

    float4 a0 = {0.f, 0.f, 0.f, 0.f}, a1 = a0, a2 = a0, a3 = a0;
#pragma unroll
    for (int i = 0; i < 16; i += 4) {
        const float4 v0 = p4[(size_t)(i + 0) * 64];
        const float4 v1 = p4[(size_t)(i + 1) * 64];
        const float4 v2 = p4[(size_t)(i + 2) * 64];
        const float4 v3 = p4[(size_t)(i + 3) * 64];
        a0.x += v0.x; a0.y += v0.y; a0.z += v0.z; a0.w += v0.w;
        a1.x += v1.x; a1.y += v1.y; a1.z += v1.z; a1.w += v1.w;
        a2.x += v2.x; a2.y += v2.y; a2.z += v2.z; a2.w += v2.w;
        a3.x += v3.x; a3.y += v3.y; a3.z += v3.z; a3.w += v3.w;
    }
    float4 r;
    r.x = (a0.x + a1.x) + (a2.x + a3.x);
    r.y = (a0.y + a1.y) + (a2.y + a3.y);
    r.z = (a0.z + a1.z) + (a2.z + a3.z);
    r.w = (a0.w + a1.w) + (a2.w + a3.w);

    __shared__ float4 red[4][64];
    red[sg][q] = r;
    __syncthreads();
    if (t < 64) {
        const float4 u0 = red[0][q], u1 = red[1][q], u2 = red[2][q], u3 = red[3][q];
        float4 o;
        o.x = (u0.x + u1.x) + (u2.x + u3.x);
        o.y = (u0.y + u1.y) + (u2.y + u3.y);
        o.z = (u0.z + u1.z) + (u2.z + u3.z);
        o.w = (u0.w + u1.w) + (u2.w + u3.w);
        float* d = att + ((size_t)b * CC + 4 * q) * KK + k;
        d[0 * KK] = o.x;
        d[1 * KK] = o.y;
        d[2 * KK] = o.z;
        d[3 * KK] = o.w;
    }
}

// ---- K2: gate + apply (frozen since round 2) ----
#define S2 8                 // hw splits
#define CT2 16               // channels per block
#define CHUNK24 (HW4 / S2)   // 512 float4

__global__ __launch_bounds__(256) void CGM_k2_apply(
    const float* __restrict__ feature,
    const float* __restrict__ gamma,
    const float* __restrict__ att,
    float* __restrict__ out)
{
    const int bI = blockIdx.x;
    const int ct = bI & 15;
    const int s  = (bI >> 4) & (S2 - 1);
    const int b  = bI >> 7;
    const int t  = threadIdx.x;
    const int c0 = ct * CT2;

    __shared__ float sgk[CT2 * KK];
    __shared__ float scale[CT2];

    // NOTE: CT2*KK = 304 > 256 threads — MUST be a strided loop, not `if`.
    for (int idx = t; idx < CT2 * KK; idx += 256) {
        const int c = idx / KK;
        const int k = idx - c * KK;
        const float a = att[(size_t)(b * CC + c0 + c) * KK + k];
        const float sig = 1.f / (1.f + __expf(-a));
        sgk[idx] = sig * gamma[k];
    }
    __syncthreads();

    if (t < CT2) {
        float ssum = 0.f;
#define ADDK(K) ssum += sgk[t * KK + (K)];
        FOR_K(ADDK)
#undef ADDK
        scale[t] = 1.f + ssum;
    }
    __syncthreads();

    const float4* f4 = (const float4*)feature + (size_t)(b * CC + c0) * HW4;
    float4*       o4 = (float4*)out           + (size_t)(b * CC + c0) * HW4;
    const int ibase = s * CHUNK24;
#pragma unroll
    for (int c = 0; c < CT2; ++c) {
        const float sc = scale[c];
#pragma unroll
        for (int r = 0; r < CHUNK24 / 256; ++r) {   // 2 iterations
            const int i = ibase + r * 256 + t;
            const float4 f = f4[(size_t)c * HW4 + i];
            float4 o;
            o.x = f.x * sc;
            o.y = f.y * sc;
            o.z = f.z * sc;
            o.w = f.w * sc;
            o4[(size_t)c * HW4 + i] = o;
        }
    }
}

extern "C" void kernel_launch(void* const* d_in, const int* in_sizes, int n_in,
                              void* d_out, int out_size, void* d_ws, size_t ws_size,
                              hipStream_t stream) {
    const float* feature = (const float*)d_in[0];
    const float* map_    = (const float*)d_in[1];
    const float* gamma   = (const float*)d_in[2];
    float* out           = (float*)d_out;
    float* att           = (float*)d_ws;   // BB*CC*KK*4 = 155,648 B

    const size_t att_bytes  = (size_t)BB * CC * KK * sizeof(float);
    const size_t part_off   = (att_bytes + 255) & ~(size_t)255;
    const size_t part_bytes = (size_t)KK * BB * NS2 * CC * sizeof(float); // 9,961,472 B
    const bool   split      = ws_size >= part_off + part_bytes;
    float* part = split ? (float*)((char*)d_ws + part_off) : nullptr;

    if (!split) {
        // att is re-poisoned to 0xAA before every launch — atomic fallback
        // needs it zeroed (hipMemsetAsync on stream is graph-capture safe).
        hipMemsetAsync(att, 0, att_bytes, stream);
    }

    const int grid1 = BB * NS2;               // 512
    CGM_k1_contract<<<grid1, 256, 0, stream>>>(feature, map_, att, part);

    if (split) {
        CGM_k1b_reduce<<<BB * KK, 256, 0, stream>>>(part, att);
    }

    const int grid2 = BB * S2 * (CC / CT2);   // 1024
    CGM_k2_apply<<<grid2, 256, 0, stream>>>(feature, gamma, att, out);
}

// Round 13
// 288.956 us; speedup vs baseline: 1.0878x; 1.0878x over previous
//
#include <hip/hip_runtime.h>
#include <math.h>

#define BB 8
#define CC 256
#define KK 19
#define HW 16384
#define HW4 4096            // HW / 4 (float4 units)

#define CHUNK4 32           // float4 per hw-chunk = 128 floats
#define NS (HW4 / CHUNK4)   // 128 chunks per batch

// ---- K1 history ----
// r1: 93 us. r2/r3: VGPR-pin -> scratch GBs. r4/r5: asm s_load + per-j
//     drain: 100 us. r6: 5-row SGPR map + global_load_lds staging + swizzle
//     + 4-barrier dbuf: K1 75-80, total 281 (BEST). r7: DS halved -> no
//     change. r8: no-LDS gather: 134. r9: asm pipeline: crash. r10: drains
//     halved -> no change. r11: 8 barriers + 2x occupancy -> worse.
// r12: 19-row map + wave-private counted vmcnt: 128 us, VGPR=104 -> compiler
//     put map in VGPRs via VMEM (19 rows > SGPR budget) -> map loads share
//     vmcnt with staging -> every j drained the pipeline. LAW: map rows
//     <= 5/wave for the true SGPR path; k-split is mandatory.
// Monotone evidence: barriers/block {8: worse, 4: base, 1: untried}.
// r13 (this): ONE barrier per block. Block = 64 ch x 128-float chunk;
//     single 32 KB tile [64][32]f4, staged once (8 global_load_lds/wave,
//     each 2 CONTIGUOUS 512B rows = scatter-2 vs r6's scatter-8), one
//     __syncthreads (the only vmcnt drain), then 32 j of r6-style compute
//     (5-row SGPR map, pair-batched; 1 conflict-free swizzled ds_read/j;
//     acc[5]). Grid 4096, LDS-capped 5 blocks/CU: the per-block drain hides
//     under 4 other blocks' long compute.

typedef float f32x4 __attribute__((ext_vector_type(4)));

#define AS1C(p) ((const __attribute__((address_space(1))) void*)(p))
#define AS3(p)  ((__attribute__((address_space(3))) void*)(p))

// Constant-AS vector pointer: uniform address + read-only memory -> s_load.
typedef const __attribute__((address_space(4))) f32x4* cvec4p;
#define CVEC4(p) ((cvec4p)(unsigned long long)(p))

// Per-wave uniform pointer: readfirstlane both halves (wave-uniform by
// construction; w = t>>6 is constant within a wave).
static __device__ __forceinline__ const float* uniform_ptr(const float* p) {
    unsigned long long u = (unsigned long long)p;
    unsigned lo = __builtin_amdgcn_readfirstlane((unsigned)u);
    unsigned hi = __builtin_amdgcn_readfirstlane((unsigned)(u >> 32));
    return (const float*)(((unsigned long long)hi << 32) | lo);
}

__global__ __launch_bounds__(256) void CGM_k1_contract(
    const float* __restrict__ feature,
    const float* __restrict__ map_,
    float* __restrict__ att,        // fallback target (pre-zeroed)
    float* __restrict__ part)       // [KK][BB][NS][CC] partials, or nullptr
{
    const int bI = blockIdx.x;      // ((b*NS + s) << 2) | q4
    const int q4 = bI & 3;          // channel quarter: c in [q4*64, q4*64+64)
    const int s  = (bI >> 2) & (NS - 1);
    const int b  = bI >> 9;
    const int t  = threadIdx.x;
    const int l  = t & 63;          // this thread's row (channel q4*64 + l)
    const int w  = t >> 6;          // wave id 0..3 -> k-group klo = 5w

    // Single 32 KB tile [64 rows][32 float4]; no double buffer.
    __shared__ float4 tile[2048];

    const int klo = w * 5;          // 0,5,10,15
    const float* mw_raw = map_ + (size_t)b * KK * HW + (size_t)klo * HW
                        + (size_t)s * (CHUNK4 * 4);
    // 5th row: k=klo+4, except wave 3 re-loads k=18 (dup, never stored).
    const size_t k4off = (size_t)((w == 3) ? 3 : 4) * HW;
    const float* mw  = uniform_ptr(mw_raw);
    const float* m4b = uniform_ptr(mw_raw + k4off);

    // Constant-AS row pointers -> compiler-scheduled s_load_dwordx4
    // (<=5 rows: the validated SGPR path; 19 rows falls back to VMEM, r12).
    cvec4p cm0 = CVEC4(mw);
    cvec4p cm1 = CVEC4(mw + 1 * (size_t)HW);
    cvec4p cm2 = CVEC4(mw + 2 * (size_t)HW);
    cvec4p cm3 = CVEC4(mw + 3 * (size_t)HW);
    cvec4p cm4 = CVEC4(m4b);

    const float4* fbase = (const float4*)feature
                        + ((size_t)b * CC + q4 * 64) * HW4 + s * CHUNK4;

    // Stage the whole tile: wave w covers rows 16w..16w+15 with 8 issues,
    // each issue = 2 contiguous 512 B rows (scatter-2). Dest slot is
    // lane-linear (512w + 64q + l). Source f4 index carries the inverse
    // read-swizzle within each 128 B octet: src = (u&24) | ((u^row)&7),
    // so LDS[row][u] = G[row][(u&24)|((u^row)&7)].
#pragma unroll
    for (int q = 0; q < 8; ++q) {
        const int row = 16 * w + 2 * q + (l >> 5);
        const int u   = l & 31;
        const int src = (u & 24) | ((u ^ row) & 7);
        const float4* g = fbase + (size_t)row * HW4 + src;
        __builtin_amdgcn_global_load_lds(AS1C(g),
            AS3(&tile[row * 32 + u]), 16, 0, 0);
    }

    float A0 = 0.f, A1 = 0.f, A2 = 0.f, A3 = 0.f, A4 = 0.f;

    // THE one barrier: drains staging (implicit vmcnt 0) + syncs waves.
    __syncthreads();

    // 32 j in pairs: both j's 5 map quads batched (one lgkm group per pair),
    // one swizzled ds_read_b128 per j. Read: LDS[l][(j&24)|((j^l)&7)] =
    // G[l][j]; lanes' low-3 XOR spreads each octet over all 32 banks
    // (2-way across 64 lanes = free).
#pragma unroll
    for (int jp = 0; jp < 16; ++jp) {
        const int j0 = jp * 2;
        const int j1 = jp * 2 + 1;
        const f32x4 n00 = cm0[j0];
        const f32x4 n01 = cm1[j0];
        const f32x4 n02 = cm2[j0];
        const f32x4 n03 = cm3[j0];
        const f32x4 n04 = cm4[j0];
        const f32x4 n10 = cm0[j1];
        const f32x4 n11 = cm1[j1];
        const f32x4 n12 = cm2[j1];
        const f32x4 n13 = cm3[j1];
        const f32x4 n14 = cm4[j1];
        const float4 f0 = tile[l * 32 + ((j0 & 24) | ((j0 ^ l) & 7))];
        const float4 f1 = tile[l * 32 + ((j1 & 24) | ((j1 ^ l) & 7))];
        A0 += f0.x * n00.x + f0.y * n00.y + f0.z * n00.z + f0.w * n00.w;
        A1 += f0.x * n01.x + f0.y * n01.y + f0.z * n01.z + f0.w * n01.w;
        A2 += f0.x * n02.x + f0.y * n02.y + f0.z * n02.z + f0.w * n02.w;
        A3 += f0.x * n03.x + f0.y * n03.y + f0.z * n03.z + f0.w * n03.w;
        A4 += f0.x * n04.x + f0.y * n04.y + f0.z * n04.z + f0.w * n04.w;
        A0 += f1.x * n10.x + f1.y * n10.y + f1.z * n10.z + f1.w * n10.w;
        A1 += f1.x * n11.x + f1.y * n11.y + f1.z * n11.z + f1.w * n11.w;
        A2 += f1.x * n12.x + f1.y * n12.y + f1.z * n12.z + f1.w * n12.w;
        A3 += f1.x * n13.x + f1.y * n13.y + f1.z * n13.z + f1.w * n13.w;
        A4 += f1.x * n14.x + f1.y * n14.y + f1.z * n14.z + f1.w * n14.w;
    }

    const int cbase = q4 * 64 + l;
    if (part) {
        // part[k][b][s][c]: per k one coalesced 256 B store.
#define STK(KI, AV) if (klo + (KI) < KK) {                               \
        part[((size_t)((klo + (KI)) * BB + b) * NS + s) * CC + cbase] = AV; }
        STK(0, A0) STK(1, A1) STK(2, A2) STK(3, A3) STK(4, A4)
#undef STK
    } else {
        // Fallback: fp32 atomics into pre-zeroed att.
#define STK(KI, AV) if (klo + (KI) < KK) {                               \
        atomicAdd(&att[(size_t)(b * CC + cbase) * KK + klo + (KI)], AV); }
        STK(0, A0) STK(1, A1) STK(2, A2) STK(3, A3) STK(4, A4)
#undef STK
    }
}

// ---- K1b: fold the NS=128 hw-chunk partials into att (validated r1-r11). ----
__global__ __launch_bounds__(256) void CGM_k1b_reduce(
    const float* __restrict__ part,
    float* __restrict__ att)
{
    const int bk = blockIdx.x;      // b*KK + k
    const int b  = bk / KK;
    const int k  = bk - b * KK;
    const int t  = threadIdx.x;
    const int q  = t & 63;          // float4 column: channels 4q..4q+3
    const int sg = t >> 6;          // s quarter: 32 rows

    const float4* p4 = (const float4*)(part + (size_t)(k * BB + b) * NS * CC)
                     + (size_t)(sg * 32) * 64 + q;

    float4 a0 = {0.f, 0.f, 0.f, 0.f}, a1 = a0, a2 = a0, a3 = a0;
#pragma unroll 2
    for (int i = 0; i < 32; i += 4) {
        const float4 v0 = p4[(size_t)(i + 0) * 64];
        const float4 v1 = p4[(size_t)(i + 1) * 64];
        const float4 v2 = p4[(size_t)(i + 2) * 64];
        const float4 v3 = p4[(size_t)(i + 3) * 64];
        a0.x += v0.x; a0.y += v0.y; a0.z += v0.z; a0.w += v0.w;
        a1.x += v1.x; a1.y += v1.y; a1.z += v1.z; a1.w += v1.w;
        a2.x += v2.x; a2.y += v2.y; a2.z += v2.z; a2.w += v2.w;
        a3.x += v3.x; a3.y += v3.y; a3.z += v3.z; a3.w += v3.w;
    }
    float4 r;
    r.x = (a0.x + a1.x) + (a2.x + a3.x);
    r.y = (a0.y + a1.y) + (a2.y + a3.y);
    r.z = (a0.z + a1.z) + (a2.z + a3.z);
    r.w = (a0.w + a1.w) + (a2.w + a3.w);

    __shared__ float4 red[4][64];
    red[sg][q] = r;
    __syncthreads();
    if (t < 64) {
        const float4 u0 = red[0][q], u1 = red[1][q], u2 = red[2][q], u3 = red[3][q];
        float4 o;
        o.x = (u0.x + u1.x) + (u2.x + u3.x);
        o.y = (u0.y + u1.y) + (u2.y + u3.y);
        o.z = (u0.z + u1.z) + (u2.z + u3.z);
        o.w = (u0.w + u1.w) + (u2.w + u3.w);
        float* d = att + ((size_t)b * CC + 4 * q) * KK + k;
        d[0 * KK] = o.x;
        d[1 * KK] = o.y;
        d[2 * KK] = o.z;
        d[3 * KK] = o.w;
    }
}

// ---- K2: gate + apply (frozen since round 2) ----
#define S2 8                 // hw splits
#define CT2 16               // channels per block
#define CHUNK24 (HW4 / S2)   // 512 float4

#define FOR_K(OP) OP(0) OP(1) OP(2) OP(3) OP(4) OP(5) OP(6) OP(7) OP(8) OP(9) \
                  OP(10) OP(11) OP(12) OP(13) OP(14) OP(15) OP(16) OP(17) OP(18)

__global__ __launch_bounds__(256) void CGM_k2_apply(
    const float* __restrict__ feature,
    const float* __restrict__ gamma,
    const float* __restrict__ att,
    float* __restrict__ out)
{
    const int bI = blockIdx.x;
    const int ct = bI & 15;
    const int s  = (bI >> 4) & (S2 - 1);
    const int b  = bI >> 7;
    const int t  = threadIdx.x;
    const int c0 = ct * CT2;

    __shared__ float sgk[CT2 * KK];
    __shared__ float scale[CT2];

    // NOTE: CT2*KK = 304 > 256 threads — MUST be a strided loop, not `if`.
    for (int idx = t; idx < CT2 * KK; idx += 256) {
        const int c = idx / KK;
        const int k = idx - c * KK;
        const float a = att[(size_t)(b * CC + c0 + c) * KK + k];
        const float sig = 1.f / (1.f + __expf(-a));
        sgk[idx] = sig * gamma[k];
    }
    __syncthreads();

    if (t < CT2) {
        float ssum = 0.f;
#define ADDK(K) ssum += sgk[t * KK + (K)];
        FOR_K(ADDK)
#undef ADDK
        scale[t] = 1.f + ssum;
    }
    __syncthreads();

    const float4* f4 = (const float4*)feature + (size_t)(b * CC + c0) * HW4;
    float4*       o4 = (float4*)out           + (size_t)(b * CC + c0) * HW4;
    const int ibase = s * CHUNK24;
#pragma unroll
    for (int c = 0; c < CT2; ++c) {
        const float sc = scale[c];
#pragma unroll
        for (int r = 0; r < CHUNK24 / 256; ++r) {   // 2 iterations
            const int i = ibase + r * 256 + t;
            const float4 f = f4[(size_t)c * HW4 + i];
            float4 o;
            o.x = f.x * sc;
            o.y = f.y * sc;
            o.z = f.z * sc;
            o.w = f.w * sc;
            o4[(size_t)c * HW4 + i] = o;
        }
    }
}

extern "C" void kernel_launch(void* const* d_in, const int* in_sizes, int n_in,
                              void* d_out, int out_size, void* d_ws, size_t ws_size,
                              hipStream_t stream) {
    const float* feature = (const float*)d_in[0];
    const float* map_    = (const float*)d_in[1];
    const float* gamma   = (const float*)d_in[2];
    float* out           = (float*)d_out;
    float* att           = (float*)d_ws;   // BB*CC*KK*4 = 155,648 B

    const size_t att_bytes  = (size_t)BB * CC * KK * sizeof(float);
    const size_t part_off   = (att_bytes + 255) & ~(size_t)255;
    const size_t part_bytes = (size_t)KK * BB * NS * CC * sizeof(float); // 19,922,944 B
    const bool   split      = ws_size >= part_off + part_bytes;
    float* part = split ? (float*)((char*)d_ws + part_off) : nullptr;

    if (!split) {
        // att is re-poisoned to 0xAA before every launch — atomic fallback
        // needs it zeroed (hipMemsetAsync on stream is graph-capture safe).
        hipMemsetAsync(att, 0, att_bytes, stream);
    }

    const int grid1 = BB * NS * 4;            // 4096 (channel quarters)
    CGM_k1_contract<<<grid1, 256, 0, stream>>>(feature, map_, att, part);

    if (split) {
        CGM_k1b_reduce<<<BB * KK, 256, 0, stream>>>(part, att);
    }

    const int grid2 = BB * S2 * (CC / CT2);   // 1024
    CGM_k2_apply<<<grid2, 256, 0, stream>>>(feature, gamma, att, out);
}